// Round 5
// baseline (130.494 us; speedup 1.0000x reference)
//
#include <hip/hip_runtime.h>
#include <math.h>

// Canny-style Sobel NMS + double threshold on 4096x4096 f32.
// Reference's direction predicate b1 is vacuously true (radians vs degree
// thresholds) -> NMS always compares horizontal neighbors.
//
// R5: 16 px/thread (16K waves, half of R4). No OOB selects: chunk offsets
// clamped, zero-pad handled by zeroing the two edge t-columns for the 2 edge
// lanes. NMS + double-threshold done EXACTLY in the squared-magnitude domain:
//  - s = IEEE sqrtf is monotone, so qc>=qp implies s(qc)>=s(qp); the only
//    mismatch case (qc<qp but sqrts round equal) is confined to |bits(qp)-
//    bits(qc)| <= ~5; an integer hazard net (+-8 ulp) reroutes those waves
//    to the literal sqrtf reference path (~0.1% of waves).
//  - e > 0.15f  <=>  q > 0x3CB851ED  (midpoint(0.15f, next)^2 boundary,
//    tie-to-even verified: 0.15f mantissa even)
//  - e >= 0.05f <=>  q > 0x3B23D709  (midpoint(prev, 0.05f)^2 boundary,
//    tie rounds to even prev < 0.05f)
//  - pass-through outputs (keep && 0 < e < 0.05, P~1e-6/px) need the exact
//    sqrt value -> also routed to the exact path.

constexpr int Wd = 4096;
constexpr int Ht = 4096;

typedef float f4 __attribute__((ext_vector_type(4)));

__global__ __launch_bounds__(256) void canny_kernel(const float* __restrict__ x,
                                                    float* __restrict__ out) {
    const int tid   = threadIdx.x;
    const int lane  = tid & 63;
    const int r     = blockIdx.y * 4 + (tid >> 6);      // one row per wave
    const int cbase = blockIdx.x * 1024 + lane * 16;    // 16 contiguous cols/lane

    const int rm = r > 0 ? r - 1 : 0;            // outputs at r=0 / Ht-1 are
    const int rp = r < Ht - 1 ? r + 1 : Ht - 1;  // forced 0, so clamp is safe

    const float* rowa = x + (size_t)rm * Wd;
    const float* rowb = x + (size_t)r  * Wd;
    const float* rowc = x + (size_t)rp * Wd;

    // 6 aligned float4 chunks/row covering window cols cbase-4 .. cbase+19,
    // clamped into [0, Wd-4]: no OOB, no per-element predication. Only lane 0
    // of block-x 0 and lane 63 of the last block-x are affected by the clamp,
    // and their garbage t-columns are fixed below.
    int off[6];
    #pragma unroll
    for (int k = 0; k < 6; ++k) {
        int c = cbase - 4 + 4 * k;
        off[k] = c < 0 ? 0 : (c > Wd - 4 ? Wd - 4 : c);
    }

    float ar[24], br[24], cr[24];
    #pragma unroll
    for (int k = 0; k < 6; ++k) {
        *(f4*)(ar + 4 * k) = *(const f4*)(rowa + off[k]);
        *(f4*)(br + 4 * k) = *(const f4*)(rowb + off[k]);
        *(f4*)(cr + 4 * k) = *(const f4*)(rowc + off[k]);
    }

    // Vertical pass: t[j] at image col cbase-2+j (j=0..19).
    // t1 = a+2b+c (gx smooth), t2 = a-c (gy diff). Exact: 2*b is exact, so
    // fma contraction cannot change bits vs mul+add here.
    float t1[20], t2[20];
    #pragma unroll
    for (int j = 0; j < 20; ++j) {
        float a = ar[j + 2], b = br[j + 2], c = cr[j + 2];
        t1[j] = a + 2.0f * b + c;
        t2[j] = a - c;
    }

    // Zero-pad fixes: t at cols -2,-1 (left edge) and 4096,4097 (right edge)
    // are all-zero in the reference conv (input col OOB -> 0).
    if (blockIdx.x == 0 && lane == 0) {
        t1[0] = 0.f; t2[0] = 0.f; t1[1] = 0.f; t2[1] = 0.f;
    }
    if (blockIdx.x == 3 && lane == 63) {
        t1[18] = 0.f; t2[18] = 0.f; t1[19] = 0.f; t2[19] = 0.f;
    }

    // Squared gradient magnitude q[i] at image col cbase-1+i (i=0..17).
    // Same expression text as the bit-exact R4 kernel's sqrt argument.
    float q[18];
    #pragma unroll
    for (int i = 0; i < 18; ++i) {
        float gx = t1[i + 2] - t1[i];
        float gy = t2[i] + 2.0f * t2[i + 1] + t2[i + 2];
        q[i] = gx * gx + gy * gy;
    }

    const float C1  = __uint_as_float(0x3CB851EDu);  // q > C1  <=> e > 0.15f
    const float C2B = __uint_as_float(0x3B23D709u);  // q > C2B <=> e >= 0.05f

    // Hazard net: adjacent q's within +-8 ulp could round to equal sqrts
    // (actual bin width <= ~5 f32 values); route the wave to the exact path.
    bool hazard = false;
    #pragma unroll
    for (int i = 0; i < 17; ++i) {
        int d = (int)(__float_as_uint(q[i + 1]) - __float_as_uint(q[i]));
        hazard |= ((unsigned)(d + 8) < 17u);   // d in [-8, 8] (0 harmless)
    }

    float acc[16];
    #pragma unroll
    for (int o = 0; o < 16; ++o) {
        float qp = q[o], qc = q[o + 1], qn = q[o + 2];
        bool keep = (qc >= qp) && (qc >= qn);
        acc[o] = (keep && qc > C1) ? 255.0f : 0.0f;
        // pass-through case needs the exact sqrt value
        hazard |= (keep && qc > 0.0f && qc <= C2B);
    }

    if (__any(hazard)) {
        // Exact reference path (rare: ~0.1% of waves).
        float m[18];
        #pragma unroll
        for (int i = 0; i < 18; ++i) m[i] = sqrtf(q[i]);
        #pragma unroll
        for (int o = 0; o < 16; ++o) {
            float mc = m[o + 1];
            bool keep = (mc >= m[o]) && (mc >= m[o + 2]);
            float e = keep ? mc : 0.0f;
            acc[o] = (e > 0.15f) ? 255.0f : ((e >= 0.05f) ? 0.0f : e);
        }
    }

    // Zero border shell, exactly as the reference.
    if (r == 0 || r == Ht - 1) {
        #pragma unroll
        for (int o = 0; o < 16; ++o) acc[o] = 0.0f;
    }
    if (blockIdx.x == 0 && lane == 0)  acc[0]  = 0.0f;
    if (blockIdx.x == 3 && lane == 63) acc[15] = 0.0f;

    float* op = out + (size_t)r * Wd + cbase;
    #pragma unroll
    for (int k = 0; k < 4; ++k) {
        f4 v = {acc[4 * k], acc[4 * k + 1], acc[4 * k + 2], acc[4 * k + 3]};
        *(f4*)(op + 4 * k) = v;
    }
}

extern "C" void kernel_launch(void* const* d_in, const int* in_sizes, int n_in,
                              void* d_out, int out_size, void* d_ws, size_t ws_size,
                              hipStream_t stream) {
    const float* x = (const float*)d_in[0];
    float* out = (float*)d_out;
    dim3 grid(4, 1024);   // 4 col-bands x 1024 row-bands of 4 rows
    canny_kernel<<<grid, dim3(256), 0, stream>>>(x, out);
}

// Round 6
// 117.745 us; speedup vs baseline: 1.1083x; 1.1083x over previous
//
#include <hip/hip_runtime.h>
#include <math.h>

// Canny-style Sobel NMS + double threshold on 4096x4096 f32.
// Reference's direction predicate b1 is vacuously true -> NMS is horizontal.
//
// R6: perfect wave-level coalescing. Lane i owns float4 at base+16i: every
// global load/store is 1KB contiguous per wave (16 cache lines, the minimum).
// Vertical pass (t1=a+2b+c, t2=a-c) is column-local -> 3 coalesced loads.
// Horizontal halo (t at +-2 cols) via 8 __shfl; wave-edge lanes fetch one
// 16B chunk per row under exec mask. Exact squared-domain NMS + threshold
// (verified absmax=0.0 in R5) with integer hazard net -> rare sqrtf path.

constexpr int Wd = 4096;
constexpr int Ht = 4096;

typedef float f4 __attribute__((ext_vector_type(4)));

__global__ __launch_bounds__(256) void canny_kernel(const float* __restrict__ x,
                                                    float* __restrict__ out) {
    const int tid  = threadIdx.x;
    const int lane = tid & 63;
    const int r    = blockIdx.y * 4 + (tid >> 6);   // one row per wave
    const int wc   = blockIdx.x;                    // 256-col band, 0..15
    const int cbase = wc * 256;
    const int c     = cbase + lane * 4;             // lane's first col

    const int rm = r > 0 ? r - 1 : 0;               // border rows are zeroed
    const int rp = r < Ht - 1 ? r + 1 : Ht - 1;     // below, so clamp is safe

    const float* rowa = x + (size_t)rm * Wd;
    const float* rowb = x + (size_t)r  * Wd;
    const float* rowc = x + (size_t)rp * Wd;

    // Core loads: fully coalesced (lane stride 16B).
    f4 a  = *(const f4*)(rowa + c);
    f4 b  = *(const f4*)(rowb + c);
    f4 cc = *(const f4*)(rowc + c);

    // Vertical pass for own 4 cols.
    float t1[4], t2[4];
    #pragma unroll
    for (int j = 0; j < 4; ++j) {
        t1[j] = a[j] + 2.0f * b[j] + cc[j];
        t2[j] = a[j] - cc[j];
    }

    // Wave-edge halo t (cols cbase-2,-1 and cbase+256,+257), zero at image edge.
    float hl1[2] = {0.f, 0.f}, hl2[2] = {0.f, 0.f};
    float hr1[2] = {0.f, 0.f}, hr2[2] = {0.f, 0.f};
    if (lane == 0 && wc > 0) {
        f4 ha = *(const f4*)(rowa + cbase - 4);
        f4 hb = *(const f4*)(rowb + cbase - 4);
        f4 hc = *(const f4*)(rowc + cbase - 4);
        hl1[0] = ha[2] + 2.0f * hb[2] + hc[2];  hl2[0] = ha[2] - hc[2];
        hl1[1] = ha[3] + 2.0f * hb[3] + hc[3];  hl2[1] = ha[3] - hc[3];
    }
    if (lane == 63 && wc < 15) {
        f4 ha = *(const f4*)(rowa + cbase + 256);
        f4 hb = *(const f4*)(rowb + cbase + 256);
        f4 hc = *(const f4*)(rowc + cbase + 256);
        hr1[0] = ha[0] + 2.0f * hb[0] + hc[0];  hr2[0] = ha[0] - hc[0];
        hr1[1] = ha[1] + 2.0f * hb[1] + hc[1];  hr2[1] = ha[1] - hc[1];
    }

    // Neighbor t via shuffle: left neighbor's cols 2,3 / right neighbor's 0,1.
    float l1a = __shfl_up(t1[2], 1),  l1b = __shfl_up(t1[3], 1);
    float l2a = __shfl_up(t2[2], 1),  l2b = __shfl_up(t2[3], 1);
    float r1a = __shfl_down(t1[0], 1), r1b = __shfl_down(t1[1], 1);
    float r2a = __shfl_down(t2[0], 1), r2b = __shfl_down(t2[1], 1);
    if (lane == 0)  { l1a = hl1[0]; l1b = hl1[1]; l2a = hl2[0]; l2b = hl2[1]; }
    if (lane == 63) { r1a = hr1[0]; r1b = hr1[1]; r2a = hr2[0]; r2b = hr2[1]; }

    // T index k corresponds to image col c + (k - 2), k = 0..7.
    float T1[8] = {l1a, l1b, t1[0], t1[1], t1[2], t1[3], r1a, r1b};
    float T2[8] = {l2a, l2b, t2[0], t2[1], t2[2], t2[3], r2a, r2b};

    // Squared gradient magnitude q[i] at image col c + (i-1), i = 0..5.
    float q[6];
    #pragma unroll
    for (int i = 0; i < 6; ++i) {
        float gx = T1[i + 2] - T1[i];
        float gy = T2[i] + 2.0f * T2[i + 1] + T2[i + 2];
        q[i] = gx * gx + gy * gy;
    }

    const float C1  = __uint_as_float(0x3CB851EDu);  // q > C1  <=> sqrt(q) > 0.15f
    const float C2B = __uint_as_float(0x3B23D709u);  // q > C2B <=> sqrt(q) >= 0.05f

    // Hazard net: near-tie q pairs could flip >= after rounding sqrt; route
    // the wave to the exact path (rare).
    bool hazard = false;
    #pragma unroll
    for (int i = 0; i < 5; ++i) {
        int d = (int)(__float_as_uint(q[i + 1]) - __float_as_uint(q[i]));
        hazard |= ((unsigned)(d + 8) < 17u);
    }

    float acc[4];
    #pragma unroll
    for (int o = 0; o < 4; ++o) {
        float qp = q[o], qc = q[o + 1], qn = q[o + 2];
        bool keep = (qc >= qp) && (qc >= qn);
        acc[o] = (keep && qc > C1) ? 255.0f : 0.0f;
        hazard |= (keep && qc > 0.0f && qc <= C2B);   // pass-through needs sqrt
    }

    if (__any(hazard)) {
        float m[6];
        #pragma unroll
        for (int i = 0; i < 6; ++i) m[i] = sqrtf(q[i]);
        #pragma unroll
        for (int o = 0; o < 4; ++o) {
            float mc = m[o + 1];
            bool keep = (mc >= m[o]) && (mc >= m[o + 2]);
            float e = keep ? mc : 0.0f;
            acc[o] = (e > 0.15f) ? 255.0f : ((e >= 0.05f) ? 0.0f : e);
        }
    }

    // Zero border shell, exactly as the reference.
    if (r == 0 || r == Ht - 1) {
        #pragma unroll
        for (int o = 0; o < 4; ++o) acc[o] = 0.0f;
    }
    if (wc == 0  && lane == 0)  acc[0] = 0.0f;
    if (wc == 15 && lane == 63) acc[3] = 0.0f;

    f4 v = {acc[0], acc[1], acc[2], acc[3]};
    *(f4*)(out + (size_t)r * Wd + c) = v;   // fully coalesced store
}

extern "C" void kernel_launch(void* const* d_in, const int* in_sizes, int n_in,
                              void* d_out, int out_size, void* d_ws, size_t ws_size,
                              hipStream_t stream) {
    const float* x = (const float*)d_in[0];
    float* out = (float*)d_out;
    dim3 grid(16, 1024);   // 16 col-bands x (1024 blocks of 4 rows)
    canny_kernel<<<grid, dim3(256), 0, stream>>>(x, out);
}

// Round 7
// 113.319 us; speedup vs baseline: 1.1516x; 1.0391x over previous
//
#include <hip/hip_runtime.h>
#include <math.h>

// Canny-style Sobel NMS + double threshold on 4096x4096 f32.
// Reference's direction predicate b1 is vacuously true -> NMS is horizontal.
//
// R7: 4 cols x 8 rows per lane. A wave loads its 10 needed row-chunks (1KB,
// fully coalesced) up front -> 10 independent loads in flight, 1.25x read
// amplification (vs 3x in all previous rounds). Column halo via __shfl with
// 8B float2 edge-lane loads (R6 scheme, verified absmax 0.0). Exact
// squared-domain NMS + double threshold with integer hazard net -> rare
// sqrtf reference path. Non-temporal stores keep the write stream out of L2.

constexpr int Wd = 4096;
constexpr int Ht = 4096;
constexpr int ROWS = 8;

typedef float f4 __attribute__((ext_vector_type(4)));
typedef float f2 __attribute__((ext_vector_type(2)));

__global__ __launch_bounds__(256) void canny_kernel(const float* __restrict__ x,
                                                    float* __restrict__ out) {
    const int tid  = threadIdx.x;
    const int lane = tid & 63;
    const int wv   = tid >> 6;
    const int wc   = blockIdx.x;                 // 256-col band, 0..15
    const int cbase = wc * 256;
    const int c     = cbase + lane * 4;          // lane's first col
    const int r0    = (blockIdx.y * 4 + wv) * ROWS;  // wave's first output row

    const bool needL = (lane == 0)  && (wc > 0);
    const bool needR = (lane == 63) && (wc < 15);
    const f2 z2 = {0.f, 0.f};

    // ---- Load all rows up front: 10 coalesced f4 wave-loads + edge halos ----
    f4 X[ROWS + 2];
    f2 HL[ROWS + 2], HR[ROWS + 2];
    #pragma unroll
    for (int k = 0; k < ROWS + 2; ++k) {
        int rr = r0 - 1 + k;
        rr = rr < 0 ? 0 : (rr > Ht - 1 ? Ht - 1 : rr);   // border rows zeroed below
        const float* row = x + (size_t)rr * Wd;
        X[k]  = *(const f4*)(row + c);
        HL[k] = needL ? *(const f2*)(row + cbase - 2)   : z2;  // cols cbase-2,-1
        HR[k] = needR ? *(const f2*)(row + cbase + 256) : z2;  // cols +256,+257
    }

    const float C1  = __uint_as_float(0x3CB851EDu);  // q > C1  <=> sqrt(q) > 0.15f
    const float C2B = __uint_as_float(0x3B23D709u);  // q > C2B <=> sqrt(q) >= 0.05f

    #pragma unroll
    for (int o = 0; o < ROWS; ++o) {
        const int r = r0 + o;
        f4 a = X[o], b = X[o + 1], cc = X[o + 2];

        // Vertical pass for own 4 cols: t1 = a+2b+c (gx), t2 = a-c (gy).
        float t1[4], t2[4];
        #pragma unroll
        for (int j = 0; j < 4; ++j) {
            t1[j] = a[j] + 2.0f * b[j] + cc[j];
            t2[j] = a[j] - cc[j];
        }

        // Halo t (meaningful only on lanes 0/63; zero at image edges).
        float L1x = HL[o].x + 2.0f * HL[o + 1].x + HL[o + 2].x;
        float L1y = HL[o].y + 2.0f * HL[o + 1].y + HL[o + 2].y;
        float L2x = HL[o].x - HL[o + 2].x;
        float L2y = HL[o].y - HL[o + 2].y;
        float R1x = HR[o].x + 2.0f * HR[o + 1].x + HR[o + 2].x;
        float R1y = HR[o].y + 2.0f * HR[o + 1].y + HR[o + 2].y;
        float R2x = HR[o].x - HR[o + 2].x;
        float R2y = HR[o].y - HR[o + 2].y;

        // Neighbor t via shuffle: left lane's cols 2,3 / right lane's cols 0,1.
        float l1a = __shfl_up(t1[2], 1),   l1b = __shfl_up(t1[3], 1);
        float l2a = __shfl_up(t2[2], 1),   l2b = __shfl_up(t2[3], 1);
        float r1a = __shfl_down(t1[0], 1), r1b = __shfl_down(t1[1], 1);
        float r2a = __shfl_down(t2[0], 1), r2b = __shfl_down(t2[1], 1);
        if (lane == 0)  { l1a = L1x; l1b = L1y; l2a = L2x; l2b = L2y; }
        if (lane == 63) { r1a = R1x; r1b = R1y; r2a = R2x; r2b = R2y; }

        // T index k = image col c + (k-2), k = 0..7.
        float T1[8] = {l1a, l1b, t1[0], t1[1], t1[2], t1[3], r1a, r1b};
        float T2[8] = {l2a, l2b, t2[0], t2[1], t2[2], t2[3], r2a, r2b};

        // Squared gradient magnitude q[i] at image col c + (i-1), i = 0..5.
        float q[6];
        #pragma unroll
        for (int i = 0; i < 6; ++i) {
            float gx = T1[i + 2] - T1[i];
            float gy = T2[i] + 2.0f * T2[i + 1] + T2[i + 2];
            q[i] = gx * gx + gy * gy;
        }

        // Hazard net: near-tie q pairs could flip >= after sqrt rounding.
        bool hazard = false;
        #pragma unroll
        for (int i = 0; i < 5; ++i) {
            int d = (int)(__float_as_uint(q[i + 1]) - __float_as_uint(q[i]));
            hazard |= ((unsigned)(d + 8) < 17u);
        }

        float acc[4];
        #pragma unroll
        for (int o2 = 0; o2 < 4; ++o2) {
            float qp = q[o2], qc = q[o2 + 1], qn = q[o2 + 2];
            bool keep = (qc >= qp) && (qc >= qn);
            acc[o2] = (keep && qc > C1) ? 255.0f : 0.0f;
            hazard |= (keep && qc > 0.0f && qc <= C2B);  // pass-through needs sqrt
        }

        if (__any(hazard)) {
            // Exact reference path (rare).
            float m[6];
            #pragma unroll
            for (int i = 0; i < 6; ++i) m[i] = sqrtf(q[i]);
            #pragma unroll
            for (int o2 = 0; o2 < 4; ++o2) {
                float mc = m[o2 + 1];
                bool keep = (mc >= m[o2]) && (mc >= m[o2 + 2]);
                float e = keep ? mc : 0.0f;
                acc[o2] = (e > 0.15f) ? 255.0f : ((e >= 0.05f) ? 0.0f : e);
            }
        }

        // Zero border shell, exactly as the reference.
        if (r == 0 || r == Ht - 1) {
            #pragma unroll
            for (int o2 = 0; o2 < 4; ++o2) acc[o2] = 0.0f;
        }
        if (wc == 0  && lane == 0)  acc[0] = 0.0f;
        if (wc == 15 && lane == 63) acc[3] = 0.0f;

        f4 v = {acc[0], acc[1], acc[2], acc[3]};
        __builtin_nontemporal_store(v, (f4*)(out + (size_t)r * Wd + c));
    }
}

extern "C" void kernel_launch(void* const* d_in, const int* in_sizes, int n_in,
                              void* d_out, int out_size, void* d_ws, size_t ws_size,
                              hipStream_t stream) {
    const float* x = (const float*)d_in[0];
    float* out = (float*)d_out;
    dim3 grid(16, 128);   // 16 col-bands x 128 blocks of (4 waves x 8 rows)
    canny_kernel<<<grid, dim3(256), 0, stream>>>(x, out);
}

// Round 8
// 109.648 us; speedup vs baseline: 1.1901x; 1.0335x over previous
//
#include <hip/hip_runtime.h>
#include <math.h>

// Canny-style Sobel NMS + double threshold on 4096x4096 f32.
// Reference's direction predicate b1 is vacuously true -> NMS is horizontal.
//
// R8: TA (lane-address throughput) model. R7 spent >50% of its vector-memory
// issue on 20 exec-masked 8B halo loads per wave. Here BOTH column halos for
// all 10 rows ride in ONE masked load (lane k<10 = left f2 of row k, lane
// 32+k = right f2 of row k); per-lane halo t built with 4 shfl_down, consumed
// via 4 indexed-shfl broadcasts per row (DS pipe, which is idle). 19 memory
// instructions per wave, all full-width. Math identical to the verified
// absmax-0.0 path: exact squared-domain NMS + double threshold with integer
// hazard net -> rare sqrtf reference fallback.

constexpr int Wd = 4096;
constexpr int Ht = 4096;
constexpr int ROWS = 8;

typedef float f4 __attribute__((ext_vector_type(4)));
typedef float f2 __attribute__((ext_vector_type(2)));

__global__ __launch_bounds__(256) void canny_kernel(const float* __restrict__ x,
                                                    float* __restrict__ out) {
    const int tid  = threadIdx.x;
    const int lane = tid & 63;
    const int wv   = tid >> 6;
    const int wc   = blockIdx.x;                     // 256-col band, 0..15
    const int cbase = wc * 256;
    const int c     = cbase + lane * 4;              // lane's first col
    const int r0    = (blockIdx.y * 4 + wv) * ROWS;  // wave's first output row

    // ---- Main loads: 10 coalesced f4 row-chunks (1KB/instruction) ----
    f4 X[ROWS + 2];
    #pragma unroll
    for (int k = 0; k < ROWS + 2; ++k) {
        int rr = r0 - 1 + k;
        rr = rr < 0 ? 0 : (rr > Ht - 1 ? Ht - 1 : rr);  // border rows zeroed below
        X[k] = *(const f4*)(x + (size_t)rr * Wd + c);
    }

    // ---- Halo: ONE masked load instruction covers both sides x all rows ----
    // lane k (k<10):  left halo f2 (cols cbase-2, cbase-1) of row r0-1+k
    // lane 32+k:      right halo f2 (cols cbase+256, +257) of row r0-1+k
    // Image-edge bands load nothing -> zeros (matches the zero-pad conv).
    f2 hl = {0.f, 0.f};
    {
        const int  hk   = lane & 31;
        const bool left = lane < 32;
        const bool valid = (hk < ROWS + 2) && (left ? (wc > 0) : (wc < 15));
        if (valid) {
            int rr = r0 - 1 + hk;
            rr = rr < 0 ? 0 : (rr > Ht - 1 ? Ht - 1 : rr);
            const int hc = left ? cbase - 2 : cbase + 256;
            hl = *(const f2*)(x + (size_t)rr * Wd + hc);
        }
    }
    // Per-lane halo t: lane (side*32 + o) holds the t-halo for output row r0+o.
    // (Lanes whose shfl_down reaches past their side's rows are never consumed.)
    const float s1x = __shfl_down(hl.x, 1), s2x = __shfl_down(hl.x, 2);
    const float s1y = __shfl_down(hl.y, 1), s2y = __shfl_down(hl.y, 2);
    const float th1x = hl.x + 2.0f * s1x + s2x;   // t1 of halo col 0
    const float th1y = hl.y + 2.0f * s1y + s2y;   // t1 of halo col 1
    const float th2x = hl.x - s2x;                // t2 of halo col 0
    const float th2y = hl.y - s2y;                // t2 of halo col 1

    const float C1  = __uint_as_float(0x3CB851EDu);  // q > C1  <=> sqrt(q) > 0.15f
    const float C2B = __uint_as_float(0x3B23D709u);  // q > C2B <=> sqrt(q) >= 0.05f

    #pragma unroll
    for (int o = 0; o < ROWS; ++o) {
        const int r = r0 + o;
        f4 a = X[o], b = X[o + 1], cc = X[o + 2];

        // Vertical pass for own 4 cols: t1 = a+2b+c (gx), t2 = a-c (gy).
        float t1[4], t2[4];
        #pragma unroll
        for (int j = 0; j < 4; ++j) {
            t1[j] = a[j] + 2.0f * b[j] + cc[j];
            t2[j] = a[j] - cc[j];
        }

        // Halo broadcast: lane 0 wants left (lane o), lane 63 right (lane 32+o).
        const int hidx = (lane == 63) ? 32 + o : o;
        const float b1x = __shfl(th1x, hidx);
        const float b1y = __shfl(th1y, hidx);
        const float b2x = __shfl(th2x, hidx);
        const float b2y = __shfl(th2y, hidx);

        // Neighbor t via shuffle: left lane's cols 2,3 / right lane's cols 0,1.
        float l1a = __shfl_up(t1[2], 1),   l1b = __shfl_up(t1[3], 1);
        float l2a = __shfl_up(t2[2], 1),   l2b = __shfl_up(t2[3], 1);
        float r1a = __shfl_down(t1[0], 1), r1b = __shfl_down(t1[1], 1);
        float r2a = __shfl_down(t2[0], 1), r2b = __shfl_down(t2[1], 1);
        if (lane == 0)  { l1a = b1x; l1b = b1y; l2a = b2x; l2b = b2y; }
        if (lane == 63) { r1a = b1x; r1b = b1y; r2a = b2x; r2b = b2y; }

        // T index k = image col c + (k-2), k = 0..7.
        float T1[8] = {l1a, l1b, t1[0], t1[1], t1[2], t1[3], r1a, r1b};
        float T2[8] = {l2a, l2b, t2[0], t2[1], t2[2], t2[3], r2a, r2b};

        // Squared gradient magnitude q[i] at image col c + (i-1), i = 0..5.
        float q[6];
        #pragma unroll
        for (int i = 0; i < 6; ++i) {
            float gx = T1[i + 2] - T1[i];
            float gy = T2[i] + 2.0f * T2[i + 1] + T2[i + 2];
            q[i] = gx * gx + gy * gy;
        }

        // Hazard net: near-tie q pairs could flip >= after sqrt rounding.
        bool hazard = false;
        #pragma unroll
        for (int i = 0; i < 5; ++i) {
            int d = (int)(__float_as_uint(q[i + 1]) - __float_as_uint(q[i]));
            hazard |= ((unsigned)(d + 8) < 17u);
        }

        float acc[4];
        #pragma unroll
        for (int o2 = 0; o2 < 4; ++o2) {
            float qp = q[o2], qc = q[o2 + 1], qn = q[o2 + 2];
            bool keep = (qc >= qp) && (qc >= qn);
            acc[o2] = (keep && qc > C1) ? 255.0f : 0.0f;
            hazard |= (keep && qc > 0.0f && qc <= C2B);  // pass-through needs sqrt
        }

        if (__any(hazard)) {
            // Exact reference path (rare).
            float m[6];
            #pragma unroll
            for (int i = 0; i < 6; ++i) m[i] = sqrtf(q[i]);
            #pragma unroll
            for (int o2 = 0; o2 < 4; ++o2) {
                float mc = m[o2 + 1];
                bool keep = (mc >= m[o2]) && (mc >= m[o2 + 2]);
                float e = keep ? mc : 0.0f;
                acc[o2] = (e > 0.15f) ? 255.0f : ((e >= 0.05f) ? 0.0f : e);
            }
        }

        // Zero border shell, exactly as the reference.
        if (r == 0 || r == Ht - 1) {
            #pragma unroll
            for (int o2 = 0; o2 < 4; ++o2) acc[o2] = 0.0f;
        }
        if (wc == 0  && lane == 0)  acc[0] = 0.0f;
        if (wc == 15 && lane == 63) acc[3] = 0.0f;

        f4 v = {acc[0], acc[1], acc[2], acc[3]};
        __builtin_nontemporal_store(v, (f4*)(out + (size_t)r * Wd + c));
    }
}

extern "C" void kernel_launch(void* const* d_in, const int* in_sizes, int n_in,
                              void* d_out, int out_size, void* d_ws, size_t ws_size,
                              hipStream_t stream) {
    const float* x = (const float*)d_in[0];
    float* out = (float*)d_out;
    dim3 grid(16, 128);   // 16 col-bands x 128 blocks of (4 waves x 8 rows)
    canny_kernel<<<grid, dim3(256), 0, stream>>>(x, out);
}